// Round 12
// baseline (117.225 us; speedup 1.0000x reference)
//
#include <hip/hip_runtime.h>
#include <stdint.h>
#include <math.h>

#define BB 8
#define NN 8192
#define DD 2048
#define NITERS 50
#define NTHR 512              // router threads: 8 waves
#define EPT 16                // router: elements per thread (NN/NTHR)

typedef float f32x4 __attribute__((ext_vector_type(4)));

// Kernel 1: s[row] = dot(x[row,:], r[:]). One wave per 2 rows, 4 waves/block,
// 4096 blocks. Split cache policy: even row-pairs use nontemporal (no-allocate)
// loads -> pure HBM stream; odd row-pairs use normal loads -> their 256 MiB
// working set fits Infinity Cache exactly and stays resident across graph
// replays, serving from L3 concurrently with the HBM stream.
__global__ __launch_bounds__(256) void gemv_k(const float* __restrict__ x,
                                              const float* __restrict__ r,
                                              float* __restrict__ s) {
    const int wave = threadIdx.x >> 6;
    const int lane = threadIdx.x & 63;
    const int row = blockIdx.x * 8 + wave * 2;
    const float* x0 = x + (size_t)row * DD;

    f32x4 w[8];
#pragma unroll
    for (int j = 0; j < 8; ++j) w[j] = *reinterpret_cast<const f32x4*>(r + (j * 64 + lane) * 4);

    float a0 = 0.f, a1 = 0.f;
    const bool cached = ((row >> 1) & 1) != 0;   // odd row-pairs: allocate in L2/L3
    if (cached) {
#pragma unroll
        for (int j = 0; j < 8; ++j) {
            const int idx = (j * 64 + lane) * 4;
            const f32x4 v0 = *reinterpret_cast<const f32x4*>(x0 + idx);
            const f32x4 v1 = *reinterpret_cast<const f32x4*>(x0 + DD + idx);
            a0 = fmaf(v0.x, w[j].x, a0); a0 = fmaf(v0.y, w[j].y, a0);
            a0 = fmaf(v0.z, w[j].z, a0); a0 = fmaf(v0.w, w[j].w, a0);
            a1 = fmaf(v1.x, w[j].x, a1); a1 = fmaf(v1.y, w[j].y, a1);
            a1 = fmaf(v1.z, w[j].z, a1); a1 = fmaf(v1.w, w[j].w, a1);
        }
    } else {
#pragma unroll
        for (int j = 0; j < 8; ++j) {
            const int idx = (j * 64 + lane) * 4;
            const f32x4 v0 = __builtin_nontemporal_load(reinterpret_cast<const f32x4*>(x0 + idx));
            const f32x4 v1 = __builtin_nontemporal_load(reinterpret_cast<const f32x4*>(x0 + DD + idx));
            a0 = fmaf(v0.x, w[j].x, a0); a0 = fmaf(v0.y, w[j].y, a0);
            a0 = fmaf(v0.z, w[j].z, a0); a0 = fmaf(v0.w, w[j].w, a0);
            a1 = fmaf(v1.x, w[j].x, a1); a1 = fmaf(v1.y, w[j].y, a1);
            a1 = fmaf(v1.z, w[j].z, a1); a1 = fmaf(v1.w, w[j].w, a1);
        }
    }
#pragma unroll
    for (int off = 32; off > 0; off >>= 1) {
        a0 += __shfl_xor(a0, off, 64);
        a1 += __shfl_xor(a1, off, 64);
    }
    if (lane == 0) { s[row] = a0; s[row + 1] = a1; }
}

// fast wave-64 reduction: after this every lane holds its 32-half's sum.
__device__ __forceinline__ float halfwave_sum(float v) {
    v += __int_as_float(__builtin_amdgcn_update_dpp(0, __float_as_int(v), 0xB1, 0xF, 0xF, true));
    v += __int_as_float(__builtin_amdgcn_update_dpp(0, __float_as_int(v), 0x4E, 0xF, 0xF, true));
    v += __int_as_float(__builtin_amdgcn_update_dpp(0, __float_as_int(v), 0x141, 0xF, 0xF, true));
    v += __int_as_float(__builtin_amdgcn_update_dpp(0, __float_as_int(v), 0x140, 0xF, 0xF, true));
    v += __int_as_float(__builtin_amdgcn_ds_swizzle(__float_as_int(v), 0x401F));
    return v;
}

// Kernel 2 (UNCHANGED from round 10): multiplicative-A router.
__global__ __launch_bounds__(NTHR) void router_k(const float* __restrict__ s_in,
                                                 const int* __restrict__ ntok_p,
                                                 float* __restrict__ out) {
    __shared__ uint64_t keys[NN];                  // 64 KiB, fallback sort only
    __shared__ __align__(16) float fscr[2][16];    // ping-pong half-wave partials
    __shared__ int iscr[8];

    const int row  = blockIdx.x;
    const int tid  = threadIdx.x;
    const int lane = tid & 63;
    const int wid  = tid >> 6;
    const int ntok = ntok_p[0];

    const float LOG2E = 1.4426950408889634f;
    const float* sp = s_in + (size_t)row * NN;
    float p[EPT];
#pragma unroll
    for (int c = 0; c < 4; ++c) {
        const f32x4 v = *reinterpret_cast<const f32x4*>(sp + tid * EPT + c * 4);
        p[c * 4 + 0] = __builtin_exp2f(v.x * LOG2E);
        p[c * 4 + 1] = __builtin_exp2f(v.y * LOG2E);
        p[c * 4 + 2] = __builtin_exp2f(v.z * LOG2E);
        p[c * 4 + 3] = __builtin_exp2f(v.w * LOG2E);
    }

    const float kf = fminf((float)ntok * 1.125f, (float)NN);
    float A = kf / (float)NN;      // iteration 1 closed form

    for (int it = 1; it < NITERS; ++it) {
        float e[EPT];
#pragma unroll
        for (int j = 0; j < EPT; ++j) e[j] = fminf(p[j] * A, 1.0f);
#pragma unroll
        for (int st = 1; st < EPT; st <<= 1)
#pragma unroll
            for (int j = 0; j < EPT; j += 2 * st) e[j] += e[j + st];
        const float u = halfwave_sum(e[0]);
        float* buf = fscr[it & 1];
        if ((lane & 31) == 0) buf[wid * 2 + (lane >> 5)] = u;
        __syncthreads();
        const f32x4* b4 = reinterpret_cast<const f32x4*>(buf);
        const f32x4 q0 = b4[0], q1 = b4[1], q2 = b4[2], q3 = b4[3];
        const float U = (((q0.x + q0.y) + (q0.z + q0.w)) + ((q1.x + q1.y) + (q1.z + q1.w))) +
                        (((q2.x + q2.y) + (q2.z + q2.w)) + ((q3.x + q3.y) + (q3.z + q3.w)));
        A *= __fdividef(kf, U);    // identical in all threads -> consistent A
    }

    // membership: min(p*A,1)==1  <=> s + a >= 0 (the reference's score==1 tie set)
    int flags = 0, cnt_m = 0;
#pragma unroll
    for (int j = 0; j < EPT; ++j) {
        if (fminf(p[j] * A, 1.0f) == 1.0f) { flags |= (1 << j); ++cnt_m; }
    }

    // block-wide exclusive scan of member counts
    int xsc = cnt_m;
#pragma unroll
    for (int off = 1; off < 64; off <<= 1) {
        const int y = __shfl_up(xsc, off, 64);
        if (lane >= off) xsc += y;
    }
    if (lane == 63) iscr[wid] = xsc;
    __syncthreads();
    int wbase = 0, total = 0;
#pragma unroll
    for (int w2 = 0; w2 < 8; ++w2) {
        const int t = iscr[w2];
        if (w2 < wid) wbase += t;
        total += t;
    }
    const int base = wbase + (xsc - cnt_m);

    float* out1 = out + (size_t)BB * ntok;

    // output 0: straight-through => exactly 1.0 everywhere
    for (int q = tid; q < ntok; q += NTHR) out[(size_t)row * ntok + q] = 1.0f;

    if (total >= ntok) {
        // top-ntok are all ties at 1.0 -> lowest ntok member indices, ascending
        int pos = base;
#pragma unroll
        for (int j = 0; j < EPT; ++j) {
            if (flags & (1 << j)) {
                if (pos < ntok) out1[(size_t)row * ntok + pos] = (float)(tid * EPT + j);
                ++pos;
            }
        }
    } else {
        // fallback (not expected): exact stable top-k via bitonic sort,
        // key = (score_bits desc, index asc)
        __syncthreads();
#pragma unroll
        for (int j = 0; j < EPT; ++j) {
            const float e2 = fminf(p[j] * A, 1.0f);
            const uint32_t bits = __float_as_uint(e2);
            keys[tid * EPT + j] =
                ((uint64_t)bits << 32) | (uint32_t)(0xFFFFFFFFu - (uint32_t)(tid * EPT + j));
        }
        __syncthreads();
        for (unsigned k = 2; k <= NN; k <<= 1) {
            for (unsigned jj = k >> 1; jj > 0; jj >>= 1) {
                for (unsigned q = tid; q < NN / 2; q += NTHR) {
                    const unsigned i   = ((q & ~(jj - 1)) << 1) | (q & (jj - 1));
                    const unsigned ixj = i | jj;
                    const bool up = ((i & k) == 0);
                    const uint64_t ka = keys[i], kb = keys[ixj];
                    if ((ka < kb) == up) { keys[i] = kb; keys[ixj] = ka; }
                }
                __syncthreads();
            }
        }
        for (int q = tid; q < ntok; q += NTHR) {
            const uint32_t idx = 0xFFFFFFFFu - (uint32_t)(keys[q] & 0xFFFFFFFFull);
            out1[(size_t)row * ntok + q] = (float)idx;
        }
    }
}

extern "C" void kernel_launch(void* const* d_in, const int* in_sizes, int n_in,
                              void* d_out, int out_size, void* d_ws, size_t ws_size,
                              hipStream_t stream) {
    const float* x = (const float*)d_in[0];   // [8, 8192, 2048] f32
    const float* r = (const float*)d_in[1];   // [1, 2048] f32
    const int* ntok = (const int*)d_in[2];    // scalar int
    float* out = (float*)d_out;               // [8*ntok] scores then [8*ntok] indices
    float* s = (float*)d_ws;                  // [65536] f32 routing scores

    gemv_k<<<(BB * NN) / 8, 256, 0, stream>>>(x, r, s);
    router_k<<<BB, NTHR, 0, stream>>>(s, ntok, out);
}

// Round 13
// 106.266 us; speedup vs baseline: 1.1031x; 1.1031x over previous
//
#include <hip/hip_runtime.h>
#include <stdint.h>
#include <math.h>

#define BB 8
#define NN 8192
#define DD 2048
#define NITERS 50
#define NTHR 512              // router threads: 8 waves
#define EPT 16                // router: elements per thread (NN/NTHR)

typedef float f32x4 __attribute__((ext_vector_type(4)));
typedef __attribute__((address_space(3))) uint32_t lds_u32_t;
typedef __attribute__((address_space(1))) const uint32_t glb_u32_t;

// async global->LDS, 16 B per lane, NT (no-allocate/streaming) cache policy (aux=2).
__device__ __forceinline__ void stage16nt(const float* g, float* l) {
    __builtin_amdgcn_global_load_lds((glb_u32_t*)g, (lds_u32_t*)l, 16, 0, 2);
}

// Kernel 1 (round-11 best): s[row] = dot(x[row,:], r[:]).
// 2048 blocks x 4 waves; each wave: private 2x8KiB LDS double buffer, 8 rows
// (row = wv + g*8192), deep prefetch via global_load_lds(NT), counted vmcnt.
__global__ __launch_bounds__(256) void gemv_k(const float* __restrict__ x,
                                              const float* __restrict__ r,
                                              float* __restrict__ s) {
    __shared__ float xs[4][2][DD];                // 64 KiB
    const int wid  = threadIdx.x >> 6;
    const int lane = threadIdx.x & 63;
    const int wv   = blockIdx.x * 4 + wid;        // 0..8191

    f32x4 w[8];
#pragma unroll
    for (int j = 0; j < 8; ++j) w[j] = *reinterpret_cast<const f32x4*>(r + (j * 64 + lane) * 4);

    const float* xw = x + (size_t)wv * DD;
    float* lb0 = &xs[wid][0][0];
    float* lb1 = &xs[wid][1][0];

    // prologue: stage row g=0
#pragma unroll
    for (int c = 0; c < 8; ++c) stage16nt(xw + c * 256 + lane * 4, lb0 + c * 256);

#pragma unroll
    for (int g = 0; g < 8; ++g) {
        float* cur = (g & 1) ? lb1 : lb0;
        float* nxt = (g & 1) ? lb0 : lb1;
        if (g < 7) {
            const float* xn = xw + (size_t)(g + 1) * NN * DD;
#pragma unroll
            for (int c = 0; c < 8; ++c) stage16nt(xn + c * 256 + lane * 4, nxt + c * 256);
        }
        // wait for row g's 8 loads only; keep next row's 8 (+1 pending store) in flight
        if (g == 0)      asm volatile("s_waitcnt vmcnt(8)" ::: "memory");
        else if (g == 7) asm volatile("s_waitcnt vmcnt(1)" ::: "memory");
        else             asm volatile("s_waitcnt vmcnt(9)" ::: "memory");
        __builtin_amdgcn_sched_barrier(0);

        float accA = 0.f, accB = 0.f;
#pragma unroll
        for (int j = 0; j < 8; ++j) {
            const f32x4 v = *reinterpret_cast<const f32x4*>(cur + (j * 64 + lane) * 4);
            if (j < 4) {
                accA = fmaf(v.x, w[j].x, accA); accA = fmaf(v.y, w[j].y, accA);
                accA = fmaf(v.z, w[j].z, accA); accA = fmaf(v.w, w[j].w, accA);
            } else {
                accB = fmaf(v.x, w[j].x, accB); accB = fmaf(v.y, w[j].y, accB);
                accB = fmaf(v.z, w[j].z, accB); accB = fmaf(v.w, w[j].w, accB);
            }
        }
        float acc = accA + accB;
#pragma unroll
        for (int off = 32; off > 0; off >>= 1) acc += __shfl_xor(acc, off, 64);
        if (lane == 0) s[wv + g * NN] = acc;
    }
}

// fast wave-64 reduction: after this every lane holds its 32-half's sum.
__device__ __forceinline__ float halfwave_sum(float v) {
    v += __int_as_float(__builtin_amdgcn_update_dpp(0, __float_as_int(v), 0xB1, 0xF, 0xF, true));
    v += __int_as_float(__builtin_amdgcn_update_dpp(0, __float_as_int(v), 0x4E, 0xF, 0xF, true));
    v += __int_as_float(__builtin_amdgcn_update_dpp(0, __float_as_int(v), 0x141, 0xF, 0xF, true));
    v += __int_as_float(__builtin_amdgcn_update_dpp(0, __float_as_int(v), 0x140, 0xF, 0xF, true));
    v += __int_as_float(__builtin_amdgcn_ds_swizzle(__float_as_int(v), 0x401F));
    return v;
}

// Kernel 2 (round-10/11 validated): multiplicative-A router.
// A_{t+1} = A_t * (k / U_t), U = sum min(p_i * A, 1), p_i = 2^(s_i*log2e).
__global__ __launch_bounds__(NTHR) void router_k(const float* __restrict__ s_in,
                                                 const int* __restrict__ ntok_p,
                                                 float* __restrict__ out) {
    __shared__ uint64_t keys[NN];                  // 64 KiB, fallback sort only
    __shared__ __align__(16) float fscr[2][16];    // ping-pong half-wave partials
    __shared__ int iscr[8];

    const int row  = blockIdx.x;
    const int tid  = threadIdx.x;
    const int lane = tid & 63;
    const int wid  = tid >> 6;
    const int ntok = ntok_p[0];

    const float LOG2E = 1.4426950408889634f;
    const float* sp = s_in + (size_t)row * NN;
    float p[EPT];
#pragma unroll
    for (int c = 0; c < 4; ++c) {
        const f32x4 v = *reinterpret_cast<const f32x4*>(sp + tid * EPT + c * 4);
        p[c * 4 + 0] = __builtin_exp2f(v.x * LOG2E);
        p[c * 4 + 1] = __builtin_exp2f(v.y * LOG2E);
        p[c * 4 + 2] = __builtin_exp2f(v.z * LOG2E);
        p[c * 4 + 3] = __builtin_exp2f(v.w * LOG2E);
    }

    const float kf = fminf((float)ntok * 1.125f, (float)NN);
    float A = kf / (float)NN;      // iteration 1 closed form

    for (int it = 1; it < NITERS; ++it) {
        float e[EPT];
#pragma unroll
        for (int j = 0; j < EPT; ++j) e[j] = fminf(p[j] * A, 1.0f);
#pragma unroll
        for (int st = 1; st < EPT; st <<= 1)
#pragma unroll
            for (int j = 0; j < EPT; j += 2 * st) e[j] += e[j + st];
        const float u = halfwave_sum(e[0]);
        float* buf = fscr[it & 1];
        if ((lane & 31) == 0) buf[wid * 2 + (lane >> 5)] = u;
        __syncthreads();
        const f32x4* b4 = reinterpret_cast<const f32x4*>(buf);
        const f32x4 q0 = b4[0], q1 = b4[1], q2 = b4[2], q3 = b4[3];
        const float U = (((q0.x + q0.y) + (q0.z + q0.w)) + ((q1.x + q1.y) + (q1.z + q1.w))) +
                        (((q2.x + q2.y) + (q2.z + q2.w)) + ((q3.x + q3.y) + (q3.z + q3.w)));
        A *= __fdividef(kf, U);    // identical in all threads -> consistent A
    }

    // membership: min(p*A,1)==1  <=> s + a >= 0 (the reference's score==1 tie set)
    int flags = 0, cnt_m = 0;
#pragma unroll
    for (int j = 0; j < EPT; ++j) {
        if (fminf(p[j] * A, 1.0f) == 1.0f) { flags |= (1 << j); ++cnt_m; }
    }

    // block-wide exclusive scan of member counts
    int xsc = cnt_m;
#pragma unroll
    for (int off = 1; off < 64; off <<= 1) {
        const int y = __shfl_up(xsc, off, 64);
        if (lane >= off) xsc += y;
    }
    if (lane == 63) iscr[wid] = xsc;
    __syncthreads();
    int wbase = 0, total = 0;
#pragma unroll
    for (int w2 = 0; w2 < 8; ++w2) {
        const int t = iscr[w2];
        if (w2 < wid) wbase += t;
        total += t;
    }
    const int base = wbase + (xsc - cnt_m);

    float* out1 = out + (size_t)BB * ntok;

    // output 0: straight-through => exactly 1.0 everywhere
    for (int q = tid; q < ntok; q += NTHR) out[(size_t)row * ntok + q] = 1.0f;

    if (total >= ntok) {
        // top-ntok are all ties at 1.0 -> lowest ntok member indices, ascending
        int pos = base;
#pragma unroll
        for (int j = 0; j < EPT; ++j) {
            if (flags & (1 << j)) {
                if (pos < ntok) out1[(size_t)row * ntok + pos] = (float)(tid * EPT + j);
                ++pos;
            }
        }
    } else {
        // fallback (not expected): exact stable top-k via bitonic sort,
        // key = (score_bits desc, index asc)
        __syncthreads();
#pragma unroll
        for (int j = 0; j < EPT; ++j) {
            const float e2 = fminf(p[j] * A, 1.0f);
            const uint32_t bits = __float_as_uint(e2);
            keys[tid * EPT + j] =
                ((uint64_t)bits << 32) | (uint32_t)(0xFFFFFFFFu - (uint32_t)(tid * EPT + j));
        }
        __syncthreads();
        for (unsigned k = 2; k <= NN; k <<= 1) {
            for (unsigned jj = k >> 1; jj > 0; jj >>= 1) {
                for (unsigned q = tid; q < NN / 2; q += NTHR) {
                    const unsigned i   = ((q & ~(jj - 1)) << 1) | (q & (jj - 1));
                    const unsigned ixj = i | jj;
                    const bool up = ((i & k) == 0);
                    const uint64_t ka = keys[i], kb = keys[ixj];
                    if ((ka < kb) == up) { keys[i] = kb; keys[ixj] = ka; }
                }
                __syncthreads();
            }
        }
        for (int q = tid; q < ntok; q += NTHR) {
            const uint32_t idx = 0xFFFFFFFFu - (uint32_t)(keys[q] & 0xFFFFFFFFull);
            out1[(size_t)row * ntok + q] = (float)idx;
        }
    }
}

extern "C" void kernel_launch(void* const* d_in, const int* in_sizes, int n_in,
                              void* d_out, int out_size, void* d_ws, size_t ws_size,
                              hipStream_t stream) {
    const float* x = (const float*)d_in[0];   // [8, 8192, 2048] f32
    const float* r = (const float*)d_in[1];   // [1, 2048] f32
    const int* ntok = (const int*)d_in[2];    // scalar int
    float* out = (float*)d_out;               // [8*ntok] scores then [8*ntok] indices
    float* s = (float*)d_ws;                  // [65536] f32 routing scores

    gemv_k<<<2048, 256, 0, stream>>>(x, r, s);
    router_k<<<BB, NTHR, 0, stream>>>(s, ntok, out);
}